// Round 18
// baseline (170.127 us; speedup 1.0000x reference)
//
#include <hip/hip_runtime.h>

// GNN surrogate — all-register K=16 MFMA chain, G-stage widened to 16
// independent accumulator chains (r18). r17 fixed the spill (launch_bounds
// (256,2) -> 256-reg unified budget; WRITE 180 MB -> 128 KB, 93 us). r17's
// residual stall: GSTEP was 2 chains x 8-deep dependent MFMAs with loads
// consumed immediately. Here G runs p-outer/gi-inner: 8 adj tile-pairs
// loaded per p (mergeable b128, hoistable over prior p's MFMAs), then 32
// MFMAs across 16 independent acc chains (dep depth 2 per p).
// Layout identity (verified r15-r17): mfma_f32_16x16x16f16 C-frag
// [row=quad*4+r][col=lane&15] == operand [k=quad*4+j][m|n=lane&15]; a pk4'd
// C-frag IS the next stage's operand. Zero LDS, zero barriers.
// Folds (exact): M_l = W2[l]@W1[l+1], lift into W1eff (K=3 pad 16), v, u, cp.

typedef _Float16 f16;
typedef __attribute__((ext_vector_type(8))) _Float16 half8;
typedef __attribute__((ext_vector_type(4))) _Float16 half4;
typedef __attribute__((ext_vector_type(2))) __fp16 fp16x2;
typedef __attribute__((ext_vector_type(4))) float f32x4;

namespace {
constexpr int N = 128, H = 32;
constexpr int WS_ADJB = 0;       // f16 swizzled adj tiles [8g][4p][64lane][8] (32768 B)
constexpr int WS_W0B  = 32768;   // f16 [2t][64lane][4]  W1eff B-tiles        (1024 B)
constexpr int WS_MB   = 33792;   // f16 [2l][2t][2tp][64][4] Meff B-tiles     (4096 B)
constexpr int WS_BIAS = 37888;   // f32 [3][32]
constexpr int WS_V    = 38400;   // f32 [128]
constexpr int WS_U    = 38912;   // f32 [32]
constexpr int WS_C    = 39040;   // f32 [1]
}

static __device__ __forceinline__ half4 pk4(float a, float b, float c, float d) {
  union { half4 v; fp16x2 h[2]; } u;
  u.h[0] = __builtin_amdgcn_cvt_pkrtz(a, b);
  u.h[1] = __builtin_amdgcn_cvt_pkrtz(c, d);
  return u.v;
}
static __device__ __forceinline__ half4 relupk(f32x4 c) {
  const half4 z = {};
  return __builtin_elementwise_max(pk4(c[0], c[1], c[2], c[3]), z);
}
static __device__ __forceinline__ half4 pkc(f32x4 c) {
  return pk4(c[0], c[1], c[2], c[3]);
}

#define MF(A, B, C) __builtin_amdgcn_mfma_f32_16x16x16f16((A), (B), (C), 0, 0, 0)

// ---- prep: identical to r15-r17 (verified) ----
__global__ void prep(const float* __restrict__ adj,
                     const float* __restrict__ W_lift,
                     const float* __restrict__ b_lift,
                     const float* __restrict__ W1,
                     const float* __restrict__ b1,
                     const float* __restrict__ W2,
                     const float* __restrict__ b2,
                     const float* __restrict__ W_ro,
                     const float* __restrict__ b_ro,
                     char* __restrict__ ws) {
  const int tid = threadIdx.x;
  f16* adjb  = (f16*)(ws + WS_ADJB);
  f16* w0b   = (f16*)(ws + WS_W0B);
  f16* mb    = (f16*)(ws + WS_MB);
  float* bia = (float*)(ws + WS_BIAS);
  float* v   = (float*)(ws + WS_V);
  float* u   = (float*)(ws + WS_U);
  float* cp  = (float*)(ws + WS_C);

  for (int e = tid; e < 2048; e += 256) {
    const int g = e >> 8, p = (e >> 6) & 3, lane = e & 63;
    const int lr = lane & 15, q = lane >> 4;
    const float* src = adj + (g * 16 + lr) * N;
    f16* dst = adjb + e * 8;
#pragma unroll
    for (int h = 0; h < 2; ++h)
#pragma unroll
      for (int jj = 0; jj < 4; ++jj)
        dst[h * 4 + jj] = (f16)src[(2 * p + h) * 16 + q * 4 + jj];
  }

  __shared__ float tmp[3][H][H];
  __shared__ float sred[N];
  for (int idx = tid; idx < 3 * H * H; idx += 256) {
    const int l = idx >> 10, rem = idx & 1023;
    const int k = rem >> 5, fo = rem & 31;
    float val = 0.f;
    if (l == 0) {
      if (k < 3) for (int c = 0; c < H; ++c) val += W_lift[k * H + c] * W1[c * H + fo];
    } else {
      const float* w2l = W2 + (l - 1) * H * H;
      const float* w1n = W1 + l * H * H;
      for (int c = 0; c < H; ++c) val += w2l[k * H + c] * w1n[c * H + fo];
    }
    tmp[l][k][fo] = val;
  }
  if (tid < N) {
    float s = 0.f;
    for (int i = 0; i < N; ++i) s += adj[i * N + tid];
    v[tid] = s * (1.0f / N);
    sred[tid] = s * (1.0f / N);
  }
  if (tid < H) {
    float s0 = b1[tid], s1 = b1[H + tid], s2 = b1[2 * H + tid];
    for (int c = 0; c < H; ++c) {
      s0 += b_lift[c] * W1[c * H + tid];
      s1 += b2[c] * W1[H * H + c * H + tid];
      s2 += b2[H + c] * W1[2 * H * H + c * H + tid];
    }
    bia[tid] = s0; bia[H + tid] = s1; bia[2 * H + tid] = s2;
    float su = 0.f;
    for (int c = 0; c < H; ++c) su += W2[2 * H * H + tid * H + c] * W_ro[c];
    u[tid] = su;
  }
  __syncthreads();
  for (int e = tid; e < 512; e += 256) {
    const int t = e >> 8, lane = (e >> 2) & 63, j = e & 3;
    const int lr = lane & 15, q = lane >> 4;
    w0b[e] = (f16)tmp[0][q * 4 + j][t * 16 + lr];
  }
  for (int e = tid; e < 2048; e += 256) {
    const int l = e >> 10, rem = e & 1023;
    const int t = rem >> 9, tp = (rem >> 8) & 1, lane = (rem >> 2) & 63, j = rem & 3;
    const int lr = lane & 15, q = lane >> 4;
    mb[e] = (f16)tmp[1 + l][t * 16 + q * 4 + j][tp * 16 + lr];
  }
  if (tid == 0) {
    float c2r = 0.f;
    for (int k = 0; k < H; ++k) c2r += b2[2 * H + k] * W_ro[k];
    float S = 0.f;
    for (int j = 0; j < N; ++j) S += sred[j];
    cp[0] = c2r * S + b_ro[0];
  }
}

__global__ __launch_bounds__(256, 2)
void gnn_mfma(const float* __restrict__ x,
              const char* __restrict__ ws,
              float* __restrict__ out) {
  const f16* adjb  = (const f16*)(ws + WS_ADJB);
  const f16* w0b   = (const f16*)(ws + WS_W0B);
  const f16* mb    = (const f16*)(ws + WS_MB);
  const float* bia = (const float*)(ws + WS_BIAS);
  const float* v   = (const float*)(ws + WS_V);
  const float* u   = (const float*)(ws + WS_U);
  const float* cp  = (const float*)(ws + WS_C);

  const int tid  = threadIdx.x;
  const int wave = tid >> 6;
  const int lane = tid & 63;
  const int lrow = lane & 15;
  const int quad = lane >> 4;
  const int b    = blockIdx.x * 4 + wave;

  const f32x4 zero = {0.f, 0.f, 0.f, 0.f};

  half4 tf00, tf01, tf10, tf11, tf20, tf21, tf30, tf31,
        tf40, tf41, tf50, tf51, tf60, tf61, tf70, tf71;
  half4 pf00, pf01, pf02, pf03, pf04, pf05, pf06, pf07,
        pf10, pf11, pf12, pf13, pf14, pf15, pf16, pf17;

  // ---- L0: T0[node][fout] = relu(x·W1eff + b0) ----
  {
    const half4 w0 = *(const half4*)(w0b + (0 * 64 + lane) * 4);
    const half4 w1 = *(const half4*)(w0b + (1 * 64 + lane) * 4);
    const float bb0 = bia[lrow], bb1 = bia[16 + lrow];
    const f32x4 bi0 = {bb0, bb0, bb0, bb0};
    const f32x4 bi1 = {bb1, bb1, bb1, bb1};
#define L0G(g, TF0, TF1)                                                     \
    {                                                                        \
      half4 xa = {};                                                         \
      if (quad == 0) {                                                       \
        const float* xr = x + ((size_t)b * N + (g) * 16 + lrow) * 3;         \
        xa = pk4(xr[0], xr[1], xr[2], 0.f);                                  \
      }                                                                      \
      TF0 = relupk(MF(xa, w0, bi0));                                         \
      TF1 = relupk(MF(xa, w1, bi1));                                         \
    }
    L0G(0, tf00, tf01) L0G(1, tf10, tf11) L0G(2, tf20, tf21) L0G(3, tf30, tf31)
    L0G(4, tf40, tf41) L0G(5, tf50, tf51) L0G(6, tf60, tf61) L0G(7, tf70, tf71)
#undef L0G
  }

  // ---- G stage: p-outer / gi-inner, 16 independent accumulator chains ----
  // per p: 8 contiguous-pair loads (one per gi), then 32 MFMAs (dep depth 2)
#define GP(p, TA0, TA1, TB0, TB1)                                            \
  {                                                                          \
    const f16* bp = adjb + (((p) * 64) + lane) * 8;                          \
    const half4 h0g0 = *(const half4*)(bp + 0 * 2048);                       \
    const half4 h1g0 = *(const half4*)(bp + 0 * 2048 + 4);                   \
    const half4 h0g1 = *(const half4*)(bp + 1 * 2048);                       \
    const half4 h1g1 = *(const half4*)(bp + 1 * 2048 + 4);                   \
    const half4 h0g2 = *(const half4*)(bp + 2 * 2048);                       \
    const half4 h1g2 = *(const half4*)(bp + 2 * 2048 + 4);                   \
    const half4 h0g3 = *(const half4*)(bp + 3 * 2048);                       \
    const half4 h1g3 = *(const half4*)(bp + 3 * 2048 + 4);                   \
    const half4 h0g4 = *(const half4*)(bp + 4 * 2048);                       \
    const half4 h1g4 = *(const half4*)(bp + 4 * 2048 + 4);                   \
    const half4 h0g5 = *(const half4*)(bp + 5 * 2048);                       \
    const half4 h1g5 = *(const half4*)(bp + 5 * 2048 + 4);                   \
    const half4 h0g6 = *(const half4*)(bp + 6 * 2048);                       \
    const half4 h1g6 = *(const half4*)(bp + 6 * 2048 + 4);                   \
    const half4 h0g7 = *(const half4*)(bp + 7 * 2048);                       \
    const half4 h1g7 = *(const half4*)(bp + 7 * 2048 + 4);                   \
    A00 = MF(TA0, h0g0, A00); A01 = MF(TA1, h0g0, A01);                      \
    A10 = MF(TA0, h0g1, A10); A11 = MF(TA1, h0g1, A11);                      \
    A20 = MF(TA0, h0g2, A20); A21 = MF(TA1, h0g2, A21);                      \
    A30 = MF(TA0, h0g3, A30); A31 = MF(TA1, h0g3, A31);                      \
    A40 = MF(TA0, h0g4, A40); A41 = MF(TA1, h0g4, A41);                      \
    A50 = MF(TA0, h0g5, A50); A51 = MF(TA1, h0g5, A51);                      \
    A60 = MF(TA0, h0g6, A60); A61 = MF(TA1, h0g6, A61);                      \
    A70 = MF(TA0, h0g7, A70); A71 = MF(TA1, h0g7, A71);                      \
    A00 = MF(TB0, h1g0, A00); A01 = MF(TB1, h1g0, A01);                      \
    A10 = MF(TB0, h1g1, A10); A11 = MF(TB1, h1g1, A11);                      \
    A20 = MF(TB0, h1g2, A20); A21 = MF(TB1, h1g2, A21);                      \
    A30 = MF(TB0, h1g3, A30); A31 = MF(TB1, h1g3, A31);                      \
    A40 = MF(TB0, h1g4, A40); A41 = MF(TB1, h1g4, A41);                      \
    A50 = MF(TB0, h1g5, A50); A51 = MF(TB1, h1g5, A51);                      \
    A60 = MF(TB0, h1g6, A60); A61 = MF(TB1, h1g6, A61);                      \
    A70 = MF(TB0, h1g7, A70); A71 = MF(TB1, h1g7, A71);                      \
  }
#define GSTAGE()                                                             \
  {                                                                          \
    f32x4 A00 = zero, A01 = zero, A10 = zero, A11 = zero,                    \
          A20 = zero, A21 = zero, A30 = zero, A31 = zero,                    \
          A40 = zero, A41 = zero, A50 = zero, A51 = zero,                    \
          A60 = zero, A61 = zero, A70 = zero, A71 = zero;                    \
    GP(0, tf00, tf01, tf10, tf11)                                            \
    GP(1, tf20, tf21, tf30, tf31)                                            \
    GP(2, tf40, tf41, tf50, tf51)                                            \
    GP(3, tf60, tf61, tf70, tf71)                                            \
    pf00 = pkc(A00); pf10 = pkc(A01); pf01 = pkc(A10); pf11 = pkc(A11);      \
    pf02 = pkc(A20); pf12 = pkc(A21); pf03 = pkc(A30); pf13 = pkc(A31);      \
    pf04 = pkc(A40); pf14 = pkc(A41); pf05 = pkc(A50); pf15 = pkc(A51);      \
    pf06 = pkc(A60); pf16 = pkc(A61); pf07 = pkc(A70); pf17 = pkc(A71);      \
  }

  GSTAGE()   // G0

  // L1: T1[node][fout'] = relu(P·Meff1 + c1)
  {
    const f16* mbl = mb + 0 * 1024;
    const half4 m00 = *(const half4*)(mbl + ((0 * 2 + 0) * 64 + lane) * 4);
    const half4 m01 = *(const half4*)(mbl + ((0 * 2 + 1) * 64 + lane) * 4);
    const half4 m10 = *(const half4*)(mbl + ((1 * 2 + 0) * 64 + lane) * 4);
    const half4 m11 = *(const half4*)(mbl + ((1 * 2 + 1) * 64 + lane) * 4);
    const float bb0 = bia[H + lrow], bb1 = bia[H + 16 + lrow];
    const f32x4 bi0 = {bb0, bb0, bb0, bb0};
    const f32x4 bi1 = {bb1, bb1, bb1, bb1};
#define L1G(P0, P1, TF0, TF1)                                                \
    {                                                                        \
      f32x4 c0 = MF(P0, m00, bi0); c0 = MF(P1, m10, c0);                     \
      f32x4 c1 = MF(P0, m01, bi1); c1 = MF(P1, m11, c1);                     \
      TF0 = relupk(c0); TF1 = relupk(c1);                                    \
    }
    L1G(pf00, pf10, tf00, tf01) L1G(pf01, pf11, tf10, tf11)
    L1G(pf02, pf12, tf20, tf21) L1G(pf03, pf13, tf30, tf31)
    L1G(pf04, pf14, tf40, tf41) L1G(pf05, pf15, tf50, tf51)
    L1G(pf06, pf16, tf60, tf61) L1G(pf07, pf17, tf70, tf71)
#undef L1G
  }

  GSTAGE()   // G1
#undef GSTAGE
#undef GP

  // ---- L2 + folded readout ----
  {
    const f16* mbl = mb + 1 * 1024;
    const half4 m00 = *(const half4*)(mbl + ((0 * 2 + 0) * 64 + lane) * 4);
    const half4 m01 = *(const half4*)(mbl + ((0 * 2 + 1) * 64 + lane) * 4);
    const half4 m10 = *(const half4*)(mbl + ((1 * 2 + 0) * 64 + lane) * 4);
    const half4 m11 = *(const half4*)(mbl + ((1 * 2 + 1) * 64 + lane) * 4);
    const float bb0 = bia[2 * H + lrow], bb1 = bia[2 * H + 16 + lrow];
    const f32x4 bi0 = {bb0, bb0, bb0, bb0};
    const f32x4 bi1 = {bb1, bb1, bb1, bb1};
    const float u0 = u[lrow], u1 = u[16 + lrow];
    float partial = 0.f;
#define L2G(g, P0, P1)                                                       \
    {                                                                        \
      f32x4 c0 = MF(P0, m00, bi0); c0 = MF(P1, m10, c0);                     \
      f32x4 c1 = MF(P0, m01, bi1); c1 = MF(P1, m11, c1);                     \
      const float4 vv = *(const float4*)(v + (g) * 16 + quad * 4);           \
      partial += (fmaxf(c0[0], 0.f) * vv.x + fmaxf(c0[1], 0.f) * vv.y +      \
                  fmaxf(c0[2], 0.f) * vv.z + fmaxf(c0[3], 0.f) * vv.w) * u0 +\
                 (fmaxf(c1[0], 0.f) * vv.x + fmaxf(c1[1], 0.f) * vv.y +      \
                  fmaxf(c1[2], 0.f) * vv.z + fmaxf(c1[3], 0.f) * vv.w) * u1; \
    }
    L2G(0, pf00, pf10) L2G(1, pf01, pf11) L2G(2, pf02, pf12) L2G(3, pf03, pf13)
    L2G(4, pf04, pf14) L2G(5, pf05, pf15) L2G(6, pf06, pf16) L2G(7, pf07, pf17)
#undef L2G
#pragma unroll
    for (int off = 32; off > 0; off >>= 1) partial += __shfl_down(partial, off, 64);
    if (lane == 0) out[b] = partial + cp[0];
  }
}

extern "C" void kernel_launch(void* const* d_in, const int* in_sizes, int n_in,
                              void* d_out, int out_size, void* d_ws, size_t ws_size,
                              hipStream_t stream) {
  const float* x      = (const float*)d_in[0];
  const float* adj    = (const float*)d_in[1];
  const float* W_lift = (const float*)d_in[2];
  const float* b_lift = (const float*)d_in[3];
  const float* W1     = (const float*)d_in[4];
  const float* b1     = (const float*)d_in[5];
  const float* W2     = (const float*)d_in[6];
  const float* b2     = (const float*)d_in[7];
  const float* W_ro   = (const float*)d_in[8];
  const float* b_ro   = (const float*)d_in[9];
  char* ws = (char*)d_ws;
  float* o = (float*)d_out;

  const int B = in_sizes[0] / (N * 3);   // 16384
  hipLaunchKernelGGL(prep, dim3(1), dim3(256), 0, stream,
                     adj, W_lift, b_lift, W1, b1, W2, b2, W_ro, b_ro, ws);
  hipLaunchKernelGGL(gnn_mfma, dim3(B / 4), dim3(256), 0, stream,
                     x, (const char*)ws, o);
}